// Round 2
// baseline (204.136 us; speedup 1.0000x reference)
//
#include <hip/hip_runtime.h>

// GeoCyclicPadding: x (B=2, C=192, H=360, W=720) f32, p=3
// out (B, C, 366, 726):
//   out[bc, ho, wp] = x[bc, h, w] where
//     middle (3 <= ho < 363): h = ho-3,            wr = wp
//     top    (ho < 3):        h = 2-ho,            wr = (wp+360) % 726
//     bottom (ho >= 363):     h = 722-ho,          wr = (wp+360) % 726
//     w = (wr - 3) mod 720
//
// Grid: (x: 2 blocks of 192 threads covering 363 float2 per row,
//        y: ho in [0,366), z: bc in [0,384)).
// All row-level quantities (h, halo, bases) are wave/block-uniform -> SGPRs.

__device__ __forceinline__ int src_w(int wr) {
    // wr in [0, 726): w = (wr - 3) mod 720
    int w = wr - 3;
    if (w < 0)        w += 720;
    else if (w >= 720) w -= 720;
    return w;
}

__global__ __launch_bounds__(192) void geo_pad_kernel(const float* __restrict__ x,
                                                      float* __restrict__ out) {
    constexpr int W  = 720;
    constexpr int Wp = 726;   // W + 2p
    constexpr int Hp = 366;   // H + 2p
    constexpr int H  = 360;
    constexpr int p  = 3;

    const int j  = blockIdx.x * 192 + threadIdx.x;   // float2 index in row [0,363)
    if (j >= Wp / 2) return;
    const int ho = blockIdx.y;
    const int bc = blockIdx.z;

    // block-uniform row mapping
    const bool halo = (ho < p) | (ho >= p + H);
    const int h = (ho >= p && ho < p + H) ? (ho - p)
                : (ho < p) ? (p - 1 - ho)
                           : (2 * H + p - 1 - ho);

    const float* __restrict__ srow = x + (bc * H + h) * W;
    float* __restrict__ orow = out + (bc * Hp + ho) * Wp;

    const int wp0 = 2 * j;
    int wr0 = wp0 + (halo ? W / 2 : 0);
    if (wr0 >= Wp) wr0 -= Wp;
    int wr1 = wr0 + 1;
    if (wr1 >= Wp) wr1 -= Wp;

    float2 v;
    v.x = srow[src_w(wr0)];
    v.y = srow[src_w(wr1)];
    *reinterpret_cast<float2*>(orow + wp0) = v;
}

extern "C" void kernel_launch(void* const* d_in, const int* in_sizes, int n_in,
                              void* d_out, int out_size, void* d_ws, size_t ws_size,
                              hipStream_t stream) {
    const float* x = (const float*)d_in[0];
    float* out = (float*)d_out;

    dim3 grid(2, 366, 384);   // x: 2*192=384 float2 slots for 363; y: ho; z: b*c
    dim3 block(192, 1, 1);
    geo_pad_kernel<<<grid, block, 0, stream>>>(x, out);
}

// Round 3
// 163.049 us; speedup vs baseline: 1.2520x; 1.2520x over previous
//
#include <hip/hip_runtime.h>

// GeoCyclicPadding: x (B=2, C=192, H=360, W=720) f32, p=3
// out (B, C, 366, 726):
//   out[bc, ho, wp] = x[bc, h, w]:
//     middle (3 <= ho < 363): h = ho-3,       wr = wp
//     halo   (else):          h = 2-ho (top) or 722-ho (bottom),
//                             wr = (wp + 360) mod 726
//     w = (wr - 3) mod 720
//
// Flat linear output mapping, one float4 store per thread (always 16B
// aligned). Loads: single 16B (4B-aligned) load on the contiguous fast
// path (>98% of groups), per-element fallback at wrap/row-cross points.

typedef float f4u __attribute__((ext_vector_type(4), aligned(4)));

__global__ __launch_bounds__(256) void geo_pad_kernel(const float* __restrict__ x,
                                                      float* __restrict__ out,
                                                      int nvec) {
    constexpr int W  = 720;
    constexpr int H  = 360;
    constexpr int p  = 3;
    constexpr int Wp = 726;
    constexpr int Hp = 366;

    const int stride = gridDim.x * blockDim.x;
    for (int t = blockIdx.x * blockDim.x + threadIdx.x; t < nvec; t += stride) {
        const int idx = t * 4;
        int wp = idx % Wp;
        int r  = idx / Wp;
        int ho = r % Hp;
        int bc = r / Hp;

        const bool mid = (ho >= p) & (ho < p + H);
        const int h = mid ? (ho - p) : ((ho < p) ? (p - 1 - ho) : (2 * H + p - 1 - ho));
        const float* __restrict__ srow = x + (bc * H + h) * W;

        float4 v;
        bool fast = false;
        if (wp + 3 < Wp) {                      // group stays within one row
            int wr0 = wp + (mid ? 0 : W / 2);
            if (wr0 >= Wp) wr0 -= Wp;
            int w0 = wr0 - p;
            if (w0 < 0) w0 += W; else if (w0 >= W) w0 -= W;

            int wr3 = wp + 3 + (mid ? 0 : W / 2);
            if (wr3 >= Wp) wr3 -= Wp;
            int w3 = wr3 - p;
            if (w3 < 0) w3 += W; else if (w3 >= W) w3 -= W;

            if (w3 == w0 + 3) {                 // wraps only decrease w => contiguous
                f4u tmp = *reinterpret_cast<const f4u*>(srow + w0);
                v.x = tmp.x; v.y = tmp.y; v.z = tmp.z; v.w = tmp.w;
                fast = true;
            }
        }
        if (!fast) {                            // rare: wrap or row-cross group
            float* vp = &v.x;
            int wpk = wp, hok = ho, bck = bc;
#pragma unroll
            for (int k = 0; k < 4; ++k) {
                const bool midk = (hok >= p) & (hok < p + H);
                const int hk = midk ? (hok - p)
                                    : ((hok < p) ? (p - 1 - hok) : (2 * H + p - 1 - hok));
                int wr = wpk + (midk ? 0 : W / 2);
                if (wr >= Wp) wr -= Wp;
                int w = wr - p;
                if (w < 0) w += W; else if (w >= W) w -= W;
                vp[k] = x[(bck * H + hk) * W + w];
                ++wpk;
                if (wpk == Wp) { wpk = 0; ++hok; if (hok == Hp) { hok = 0; ++bck; } }
            }
        }
        reinterpret_cast<float4*>(out)[t] = v;
    }
}

extern "C" void kernel_launch(void* const* d_in, const int* in_sizes, int n_in,
                              void* d_out, int out_size, void* d_ws, size_t ws_size,
                              hipStream_t stream) {
    const float* x = (const float*)d_in[0];
    float* out = (float*)d_out;

    const int nvec = out_size / 4;
    const int block = 256;
    int grid = (nvec + block - 1) / block;
    const int max_grid = 256 * 8;
    if (grid > max_grid) grid = max_grid;

    geo_pad_kernel<<<grid, block, 0, stream>>>(x, out, nvec);
}

// Round 4
// 147.318 us; speedup vs baseline: 1.3857x; 1.1068x over previous
//
#include <hip/hip_runtime.h>

// GeoCyclicPadding: x (B=2, C=192, H=360, W=720) f32, p=3
// out (B, C, 366, 726):
//   out[row=(bc,ho), wp] = x[bc, h, (wr-3) mod 720]
//     middle (3<=ho<363): h = ho-3,                 wr = wp
//     halo:               h = 2-ho (top) / 722-ho,  wr = (wp+360) mod 726
//
// Mapping: 182 threads per output row (181 float4 groups + 1 float2 tail).
// Groups never cross rows; contiguity check (w3==w0+3) exactly detects both
// the w-wrap (719->0) and wr-wrap (725->0) discontinuities, failing for only
// ~2 lanes per row. Stores dwordx4 (8B-aligned), non-temporal both streams.

typedef float f4u __attribute__((ext_vector_type(4), aligned(4)));
typedef float f2u __attribute__((ext_vector_type(2), aligned(8)));

__global__ __launch_bounds__(256) void geo_pad_kernel(const float* __restrict__ x,
                                                      float* __restrict__ out) {
    constexpr int W = 720, H = 360, p = 3, Wp = 726, Hp = 366;
    constexpr int TPR = 182;   // threads per output row

    const unsigned t = blockIdx.x * 256u + threadIdx.x;   // grid is exact
    const unsigned row = t / TPR;                         // [0, 384*366)
    const int j = (int)(t - row * TPR);
    const int ho = (int)(row % Hp);
    const int bc = (int)(row / Hp);

    const bool mid = (ho >= p) & (ho < p + H);
    const int h = mid ? (ho - p) : ((ho < p) ? (p - 1 - ho) : (2 * H + p - 1 - ho));
    const int off = mid ? 0 : (W / 2);

    const float* __restrict__ srow = x + ((size_t)bc * H + h) * W;
    float* __restrict__ orow = out + (size_t)row * Wp;

    if (j < TPR - 1) {
        const int wp0 = 4 * j;
        int wr0 = wp0 + off;      if (wr0 >= Wp) wr0 -= Wp;
        int wr3 = wp0 + 3 + off;  if (wr3 >= Wp) wr3 -= Wp;
        int w0 = wr0 - p; if (w0 < 0) w0 += W; else if (w0 >= W) w0 -= W;
        int w3 = wr3 - p; if (w3 < 0) w3 += W; else if (w3 >= W) w3 -= W;

        float v0, v1, v2, v3;
        if (w3 == w0 + 3) {       // contiguous (>98.9% of lanes); w0 <= 716
            f4u tmp = __builtin_nontemporal_load(
                reinterpret_cast<const f4u*>(srow + w0));
            v0 = tmp.x; v1 = tmp.y; v2 = tmp.z; v3 = tmp.w;
        } else {                  // ~2 lanes per row: per-element exact
            int wr1 = wp0 + 1 + off; if (wr1 >= Wp) wr1 -= Wp;
            int wr2 = wp0 + 2 + off; if (wr2 >= Wp) wr2 -= Wp;
            int w1 = wr1 - p; if (w1 < 0) w1 += W; else if (w1 >= W) w1 -= W;
            int w2 = wr2 - p; if (w2 < 0) w2 += W; else if (w2 >= W) w2 -= W;
            v0 = srow[w0]; v1 = srow[w1]; v2 = srow[w2]; v3 = srow[w3];
        }
        f4u sv; sv.x = v0; sv.y = v1; sv.z = v2; sv.w = v3;
        __builtin_nontemporal_store(sv, reinterpret_cast<f4u*>(orow + wp0));
    } else {
        // tail: wp = 724, 725 — always contiguous in source
        int wr0 = 724 + off; if (wr0 >= Wp) wr0 -= Wp;
        int w0 = wr0 - p; if (w0 < 0) w0 += W; else if (w0 >= W) w0 -= W;
        f2u sv; sv.x = srow[w0]; sv.y = srow[w0 + 1];
        __builtin_nontemporal_store(sv, reinterpret_cast<f2u*>(orow + 724));
    }
}

extern "C" void kernel_launch(void* const* d_in, const int* in_sizes, int n_in,
                              void* d_out, int out_size, void* d_ws, size_t ws_size,
                              hipStream_t stream) {
    const float* x = (const float*)d_in[0];
    float* out = (float*)d_out;

    // 384 planes * 366 rows * 182 threads = 25,579,008 = 99,918 * 256 exactly
    const unsigned total = 384u * 366u * 182u;
    const unsigned block = 256;
    const unsigned grid = total / block;

    geo_pad_kernel<<<grid, block, 0, stream>>>(x, out);
}

// Round 5
// 143.978 us; speedup vs baseline: 1.4178x; 1.0232x over previous
//
#include <hip/hip_runtime.h>

// GeoCyclicPadding: x (B=2, C=192, H=360, W=720) f32, p=3 -> out (B,C,366,726)
//
// Decomposition:
//  BULK (98.3%): out[bc, 3+r, 3+w] = x[bc, r, w]  for w in [0,720)
//    -> pure strided 2D copy. Thread k copies 16B-ALIGNED src group
//       x[bc,r,4k..4k+4) to out[bc,3+r,3+4k..3+4k+4) (store misaligned by
//       4 or 12 B -- unavoidable: shift is 12B, row stride 2904 % 16 == 8).
//       No wrap logic, no divergence, no slow path.
//  EDGE (1.7%): per plane: middle-row edge cols {0,1,2,723,724,725} (360x6)
//    + 6 halo rows x 726 cols, scalar with the general map:
//       h = 2-ho (top) / 722-ho (bottom); wr=(col+360)%726; w=(wr-3)%720
//
// One dispatch: blocks [0, 97200) bulk, [97200, 106974) edge -- exact
// multiples of 256 on both sides, so no intra-block path divergence.

typedef float f4a __attribute__((ext_vector_type(4), aligned(16)));
typedef float f4u __attribute__((ext_vector_type(4), aligned(4)));

__global__ __launch_bounds__(256) void geo_pad_kernel(const float* __restrict__ x,
                                                      float* __restrict__ out) {
    constexpr int W = 720, H = 360, p = 3, Wp = 726, Hp = 366;
    constexpr unsigned BULK = 384u * 360u * 180u;   // 24,883,200 (= 97,200 * 256)
    constexpr unsigned EPP  = 360u * 6u + 6u * 726u; // 6516 edge elems / plane

    const unsigned t = blockIdx.x * 256u + threadIdx.x;

    if (t < BULK) {
        // ---- bulk: aligned-load strided copy ----
        const unsigned k  = t % 180u;          // float4 group in source row
        const unsigned rr = t / 180u;
        const unsigned r  = rr % 360u;         // source row
        const unsigned bc = rr / 360u;         // plane

        const f4a* src = reinterpret_cast<const f4a*>(
            x + (size_t)(bc * 360u + r) * W) + k;
        f4a v = __builtin_nontemporal_load(src);

        float* dst = out + ((size_t)bc * Hp + (r + 3)) * Wp + 3 + 4 * k;
        f4u sv;
        sv.x = v.x; sv.y = v.y; sv.z = v.z; sv.w = v.w;
        __builtin_nontemporal_store(sv, reinterpret_cast<f4u*>(dst));
    } else {
        // ---- edges: scalar, general mapping ----
        const unsigned e  = t - BULK;
        const unsigned bc = e / EPP;
        const unsigned q  = e % EPP;

        int ho, col, h, w;
        if (q < 2160u) {                       // middle-row edge columns
            const int r  = (int)(q / 6u);
            const int c6 = (int)(q % 6u);
            ho  = r + p;
            h   = r;
            col = (c6 < 3) ? c6 : (720 + c6);          // 0,1,2 / 723,724,725
            w   = (c6 < 3) ? (717 + c6) : (c6 - 3);    // 717,718,719 / 0,1,2
        } else {                               // halo rows (full width)
            const unsigned q2 = q - 2160u;
            const int hr = (int)(q2 / (unsigned)Wp);   // 0..5
            col = (int)(q2 % (unsigned)Wp);
            ho  = (hr < p) ? hr : (H + hr);            // 0,1,2 / 363,364,365
            h   = (hr < p) ? (p - 1 - hr) : (362 - hr); // 2,1,0 / 359,358,357
            int wr = col + W / 2;
            if (wr >= Wp) wr -= Wp;
            w = wr - p;
            if (w < 0) w += W; else if (w >= W) w -= W;
        }
        out[((size_t)bc * Hp + ho) * Wp + col] =
            x[((size_t)bc * H + h) * W + w];
    }
}

extern "C" void kernel_launch(void* const* d_in, const int* in_sizes, int n_in,
                              void* d_out, int out_size, void* d_ws, size_t ws_size,
                              hipStream_t stream) {
    const float* x = (const float*)d_in[0];
    float* out = (float*)d_out;

    // bulk 24,883,200 + edge 384*6516 = 2,502,144  => 27,385,344 = 106,974 * 256
    const unsigned total = 384u * 360u * 180u + 384u * (360u * 6u + 6u * 726u);
    geo_pad_kernel<<<total / 256u, 256, 0, stream>>>(x, out);
}